// Round 12
// baseline (350.621 us; speedup 1.0000x reference)
//
#include <hip/hip_runtime.h>
#include <math.h>

// DNC MemoryAccess forward. B=8, T=16, N=512, W=64, R=4, NW=1, MODES=3, IFACE=471.
// Persistent kernel: 256 blocks (32/batch, NROW=16) x 1024 threads (16 waves/CU).
// L + LT + Mem shards in LDS; usage/prec/ww replicated (512-wide, tid<512 guards).
// ONE relaxed flag-barrier per step, early-arrive/late-poll; exchange via relaxed agent
// atomics, one burst per step. Out-drain runs on waves 8-11 concurrent with RWP matvec.

#define NBATCH 8
#define GPB    32
#define NBLK   (NBATCH*GPB)
#define BS     1024
#define NROW   16
#define NTT    16
#define NSLOT  512
#define WRD    64
#define RH     4
#define NIF    471
#define LSTR   520
#define MSTR   65
#define EPSV   1e-6f

// per-parity per-batch float offsets in exchange region (identical to R10 — proven fit)
#define B_ALO  0            // [512] allocation
#define B_WM   512          // [512][2] (write-dot, mnorm) pairs
#define B_EN   1536         // [4*512][2] (read-content exp, m0*bwd+m2*fwd) pairs
#define B_SEP  5632         // [32][4] partial sums of ER
#define B_RWP  5760         // [32][256] read-word partials
#define BATF   13952
#define IFCF   (NBATCH*NTT*NIF)     // 60288 floats of iface
#define PARF   (NBATCH*BATF)

// prs layout (16B-aligned vector fields)
#define P_ERA 328
#define P_WV  392
#define P_WS  456
#define P_FG  457
#define P_AG  461
#define P_WG  462
#define P_MOD 464
#define P_WKN 476
#define P_RKN 477

__device__ __forceinline__ float sigm(float x){ return 1.f/(1.f+expf(-x)); }
__device__ __forceinline__ float softpl(float x){ return x>0.f ? x+log1pf(expf(-x)) : log1pf(expf(x)); }
__device__ __forceinline__ float red16s(float v){ v+=__shfl_xor(v,1,16); v+=__shfl_xor(v,2,16); v+=__shfl_xor(v,4,16); v+=__shfl_xor(v,8,16); return v; }
__device__ __forceinline__ float red32s(float v){ v+=__shfl_xor(v,1,32); v+=__shfl_xor(v,2,32); v+=__shfl_xor(v,4,32); v+=__shfl_xor(v,8,32); v+=__shfl_xor(v,16,32); return v; }
__device__ __forceinline__ float red64s(float v){
  v+=__shfl_xor(v,1); v+=__shfl_xor(v,2); v+=__shfl_xor(v,4);
  v+=__shfl_xor(v,8); v+=__shfl_xor(v,16); v+=__shfl_xor(v,32); return v; }
__device__ __forceinline__ float red64m(float v){
  v*=__shfl_xor(v,1); v*=__shfl_xor(v,2); v*=__shfl_xor(v,4);
  v*=__shfl_xor(v,8); v*=__shfl_xor(v,16); v*=__shfl_xor(v,32); return v; }

__device__ __forceinline__ void stg(float* p, float v){
  __hip_atomic_store(p, v, __ATOMIC_RELAXED, __HIP_MEMORY_SCOPE_AGENT);
}
__device__ __forceinline__ float ldc(const float* p){
  return __hip_atomic_load(p, __ATOMIC_RELAXED, __HIP_MEMORY_SCOPE_AGENT);
}
__device__ __forceinline__ void stg2(float* p, float x, float y){
  union { float2 f; unsigned long long u; } v; v.f=make_float2(x,y);
  __hip_atomic_store((unsigned long long*)p, v.u, __ATOMIC_RELAXED, __HIP_MEMORY_SCOPE_AGENT);
}
__device__ __forceinline__ float2 ldc2(const float* p){
  union { float2 f; unsigned long long u; } v;
  v.u=__hip_atomic_load((const unsigned long long*)p, __ATOMIC_RELAXED, __HIP_MEMORY_SCOPE_AGENT);
  return v.f;
}

// flag slot: flg[b*512 + g*16] -- each block's flag in its own 64B line
__device__ __forceinline__ void lbar(unsigned* flg, int b, int g, unsigned gen, int tid){
  asm volatile("s_waitcnt vmcnt(0)" ::: "memory");
  __syncthreads();
  if (tid==0) __hip_atomic_store(flg+b*512+g*16, gen, __ATOMIC_RELAXED, __HIP_MEMORY_SCOPE_AGENT);
  if (tid<GPB){
    while (__hip_atomic_load(flg+b*512+tid*16, __ATOMIC_RELAXED, __HIP_MEMORY_SCOPE_AGENT) < gen)
      __builtin_amdgcn_s_sleep(1);
  }
  __syncthreads();
  asm volatile("" ::: "memory");
}

__global__ void __launch_bounds__(BS)
dnc_kernel(const float* __restrict__ ctrl, const float* __restrict__ wif,
           const float* __restrict__ bif, const float* __restrict__ mem0,
           float* __restrict__ out, float* __restrict__ ws, unsigned* __restrict__ flg)
{
  const int tid = threadIdx.x;
  const int bid = blockIdx.x;
  const int b   = bid & 7;
  const int g   = bid >> 3;        // 0..31
  const int n0  = g * NROW;

  __shared__ __align__(16) float L  [NROW*LSTR];
  __shared__ __align__(16) float LT [NROW*LSTR];
  __shared__ __align__(16) float Mem[NROW*MSTR];
  __shared__ __align__(16) float rwl[RH*NSLOT];
  __shared__ __align__(16) float wwl[NSLOT];
  __shared__ __align__(16) float usagel[NSLOT];
  __shared__ __align__(16) float precl[NSLOT];
  __shared__ __align__(16) float prs[488];
  __shared__ __align__(16) float aux[248];
  float* ern    = aux;        // [4][16]
  float* fwdb   = aux+64;     // [4][16]
  float* bwdb   = aux+128;    // [4][16]
  float* modesA = aux+192;    // [2][12] parity-banked
  float* red    = aux+216;    // [32]

  // ---------------- init ----------------
  for (int i=tid; i<NROW*LSTR; i+=BS){ L[i]=0.f; LT[i]=0.f; }
  {
    int r=tid>>6, k=tid&63;   // 16 rows x 64 = 1024 = BS
    Mem[r*MSTR+k] = mem0[(size_t)(b*NSLOT + n0 + r)*WRD + k];
  }
  if (tid<NSLOT){ usagel[tid]=0.f; precl[tid]=0.f; }
  if (g < NTT){ // iface GEMM: blocks g<16 compute iface row (b, t=g)
    float* ctrlrow = rwl;
    const float* crow = ctrl + (size_t)(b*NTT+g)*1024;
    for (int i=tid;i<1024;i+=BS) ctrlrow[i]=crow[i];
    __syncthreads();
    if (tid<NIF){
      int j=tid;
      float a0=0.f,a1=0.f,a2=0.f,a3=0.f;
      const float* wp = wif + j;
      for (int c=0;c<1024;c+=4){
        a0 += ctrlrow[c+0]*wp[(size_t)(c+0)*NIF];
        a1 += ctrlrow[c+1]*wp[(size_t)(c+1)*NIF];
        a2 += ctrlrow[c+2]*wp[(size_t)(c+2)*NIF];
        a3 += ctrlrow[c+3]*wp[(size_t)(c+3)*NIF];
      }
      ws[(size_t)(b*NTT+g)*NIF + j] = ((a0+a1)+(a2+a3)) + bif[j];
    }
  }
  __syncthreads();
  for (int i=tid;i<RH*NSLOT;i+=BS) rwl[i]=0.f;

  // heavy barrier (gen 1): makes plain-stored iface visible once
  __syncthreads();
  __builtin_amdgcn_fence(__ATOMIC_RELEASE, "agent");
  if (tid==0) __hip_atomic_store(flg+b*512+g*16, 1u, __ATOMIC_RELAXED, __HIP_MEMORY_SCOPE_AGENT);
  if (tid<GPB){
    while (__hip_atomic_load(flg+b*512+tid*16, __ATOMIC_RELAXED, __HIP_MEMORY_SCOPE_AGENT) < 1u)
      __builtin_amdgcn_s_sleep(1);
  }
  __syncthreads();
  __builtin_amdgcn_fence(__ATOMIC_ACQUIRE, "agent");

  // init publish (for step 0) into parity buffer 0
  {
    float* qb = ws + IFCF + 0*PARF + b*BATF;
    const float* ifc0 = ws + (size_t)(b*NTT+0)*NIF;
    int row=tid>>6, sub=tid&63;
    { // wc dots + mnorm on mem0 shard (64 lanes/row, 1 elem each)
      float m=Mem[row*MSTR+sub];
      float wd=m*ifc0[260+sub], ms=m*m;
      wd=red64s(wd); ms=red64s(ms);
      if (sub==0) stg2(qb+B_WM+2*(n0+row), wd, sqrtf(ms));
    }
    { // alloc_0 shard
      int n=n0+row;
      float u_n=usagel[n], pr=1.f;
      #pragma unroll
      for (int mb=0; mb<2; mb++){
        int m0=(sub+64*mb)*4;
        float4 u4=*(const float4*)&usagel[m0];
        pr *= (u4.x<u_n || (u4.x==u_n && m0  <n)) ? u4.x : 1.f;
        pr *= (u4.y<u_n || (u4.y==u_n && m0+1<n)) ? u4.y : 1.f;
        pr *= (u4.z<u_n || (u4.z==u_n && m0+2<n)) ? u4.z : 1.f;
        pr *= (u4.w<u_n || (u4.w==u_n && m0+3<n)) ? u4.w : 1.f;
      }
      pr=red64m(pr);
      if (sub==0) stg(qb+B_ALO+n, (1.f-u_n)*pr);
    }
  }
  // parse iface_0 into prs + modesA bank 0
  {
    const float* ifc = ws + (size_t)(b*NTT+0)*NIF;
    if (tid<324) prs[tid]=ifc[tid];
    __syncthreads();
    if (tid<4) prs[256+tid]=softpl(prs[256+tid]);
    else if (tid==4) prs[P_WS]=softpl(ifc[324]);
    else if (tid>=8 && tid<12) prs[P_FG+(tid-8)]=sigm(ifc[453+(tid-8)]);
    else if (tid==12) prs[P_AG]=sigm(ifc[457]);
    else if (tid==13) prs[P_WG]=sigm(ifc[458]);
    else if (tid>=16 && tid<20){
      int r=tid-16;
      float x0=ifc[459+r*3],x1=ifc[460+r*3],x2=ifc[461+r*3];
      float mx=fmaxf(x0,fmaxf(x1,x2));
      float e0=expf(x0-mx),e1=expf(x1-mx),e2=expf(x2-mx),s=e0+e1+e2;
      prs[P_MOD+r*3+0]=e0/s; prs[P_MOD+r*3+1]=e1/s; prs[P_MOD+r*3+2]=e2/s;
      modesA[r*3+0]=e0/s; modesA[r*3+1]=e1/s; modesA[r*3+2]=e2/s;
    }
    else if (tid>=64 && tid<128) prs[P_ERA+(tid-64)]=sigm(ifc[325+(tid-64)]);
    else if (tid>=192 && tid<256) prs[P_WV+(tid-192)]=ifc[389+(tid-192)];
    {
      int wv=tid>>6, lane=tid&63;
      if (wv<4){
        float v = (wv==0)? prs[260+lane] : prs[(wv-1)*64+lane];
        v = red64s(v*v);
        if (lane==0) prs[P_WKN+wv]=sqrtf(v);
        if (wv==0){
          float u=prs[192+lane];
          u=red64s(u*u);
          if (lane==0) prs[480]=sqrtf(u);
        }
      }
    }
  }
  lbar(flg, b, g, 2u, tid);

  // ---------------- time loop (t==NTT is the drain pseudo-step) ----------------
  for (int t=0; t<=NTT; t++){
    const float* pb = ws + IFCF + (t&1)*PARF + b*BATF;
    float*       qb = ws + IFCF + ((t+1)&1)*PARF + b*BATF;
    float* mprev = modesA + 12*((t+1)&1);
    float* mcur  = modesA + 12*(t&1);
    const int row = tid>>6, sub = tid&63;

    // ---- burst: ALL exchange loads + next-step write-key prefetch ----
    float2 en[4]; float2 sep2=make_float2(1.f,1.f); float rwpv=0.f;
    float2 wm=make_float2(0.f,1.f); float al=0.f; float wkv=0.f;
    if (t>0 && tid<512){
      #pragma unroll
      for (int i=0;i<4;i++) en[i]=ldc2(pb+B_EN+2*(tid+512*i));
    }
    if (t>0 && tid<64){ int gp=tid>>1, c=tid&1; sep2=ldc2(pb+B_SEP+gp*4+c*2); }
    if (t>=2 && tid>=512 && tid<768){
      int q=tid-512;
      rwpv=ldc(pb+B_RWP+(q&31)*256+g*8+(q>>5));
    }
    if (t<NTT && tid<512){
      wm=ldc2(pb+B_WM+2*tid);
      al=ldc(pb+B_ALO+tid);
    }
    if (t<NTT-1){
      const float* ifn = ws + (size_t)(b*NTT+(t+1))*NIF;
      wkv = ifn[260+sub];
    }

    // ---- A: ww-exp (regs), Se reduce, Sw partials ----
    float ewv=0.f;
    if (t<NTT && tid<512){
      ewv=expf(prs[P_WS]*wm.x/(prs[P_WKN]*wm.y+EPSV));
      wwl[tid]=ewv;
      float v=red64s(ewv);
      if ((tid&63)==0) red[4+(tid>>6)]=v;
    }
    if (t>0 && tid<64){
      float vx=sep2.x, vy=sep2.y;
      vx+=__shfl_xor(vx,2); vy+=__shfl_xor(vy,2);
      vx+=__shfl_xor(vx,4); vy+=__shfl_xor(vy,4);
      vx+=__shfl_xor(vx,8); vy+=__shfl_xor(vy,8);
      vx+=__shfl_xor(vx,16); vy+=__shfl_xor(vy,16);
      vx+=__shfl_xor(vx,32); vy+=__shfl_xor(vy,32);
      if (tid<2){ red[tid*2]=vx; red[tid*2+1]=vy; }   // Se[0..3]
    }
    __syncthreads();                                   // sync 1

    // ---- B: rwl build (+psi in regs) ----
    float psi=1.f;
    if (t>0 && tid<512){
      float rwv[4];
      #pragma unroll
      for (int i=0;i<4;i++){
        rwv[i] = en[i].y + mprev[i*3+1]*en[i].x/red[i];
        rwl[i*NSLOT+tid] = rwv[i];
      }
      psi=(1.f-prs[P_FG+0]*rwv[0])*(1.f-prs[P_FG+1]*rwv[1])
         *(1.f-prs[P_FG+2]*rwv[2])*(1.f-prs[P_FG+3]*rwv[3]);
    }
    __syncthreads();                                   // sync 2

    // ---- C: RWP (waves 0-3) ∥ out drain (waves 8-11); ww final + usage + Sww ----
    if (t>0 && tid<256){
      int r=tid>>6, k=tid&63;
      float a=0.f;
      #pragma unroll
      for (int rr=0;rr<4;rr++){
        float4 rv=*(const float4*)&rwl[r*NSLOT+n0+rr*4];
        a += rv.x*Mem[(rr*4+0)*MSTR+k] + rv.y*Mem[(rr*4+1)*MSTR+k]
           + rv.z*Mem[(rr*4+2)*MSTR+k] + rv.w*Mem[(rr*4+3)*MSTR+k];
      }
      stg(qb+B_RWP+g*256+tid, a);
    }
    if (t>=2 && tid>=512 && tid<768){
      int q=tid-512;
      float s=red32s(rwpv);
      if ((q&31)==0) out[(size_t)(b*NTT+(t-2))*256 + g*8 + (q>>5)] = s;
    }
    if (t==NTT) break;
    {
      if (tid<512){
        const float Sw=red[4]+red[5]+red[6]+red[7]+red[8]+red[9]+red[10]+red[11];
        float wwv=prs[P_WG]*(prs[P_AG]*al+(1.f-prs[P_AG])*ewv/Sw);
        wwl[tid]=wwv;
        usagel[tid]=(usagel[tid]+wwv-usagel[tid]*wwv)*psi;
        float v=red64s(wwv);
        if ((tid&63)==0) red[12+(tid>>6)]=v;
      }
    }
    __syncthreads();                                   // sync 3

    // ---- D: fused L/LT update + fwd/bwd; Mem update + rc + WM publish; alloc scan ----
    {
      float wn =wwl[n0+row];
      float pmn=precl[n0+row];
      float* Lr = &L[row*LSTR];
      float* Tr = &LT[row*LSTR];
      float fa0=0.f,fa1=0.f,fa2=0.f,fa3=0.f, ba0=0.f,ba1=0.f,ba2=0.f,ba3=0.f;
      #pragma unroll
      for (int jj=0;jj<2;jj++){
        int mb=(sub+64*jj)*4;
        float4 wm4=*(float4*)&wwl[mb];
        float4 pm4=*(float4*)&precl[mb];
        float c0=1.f-wn-wm4.x, c1=1.f-wn-wm4.y, c2=1.f-wn-wm4.z, c3=1.f-wn-wm4.w;
        int d=(n0+row)-mb;
        float4 l4=*(float4*)&Lr[mb];
        l4.x=c0*l4.x+wn*pm4.x; l4.y=c1*l4.y+wn*pm4.y;
        l4.z=c2*l4.z+wn*pm4.z; l4.w=c3*l4.w+wn*pm4.w;
        if (d>=0 && d<4) ((float*)&l4)[d]=0.f;
        *(float4*)&Lr[mb]=l4;
        float4 r0=*(const float4*)&rwl[0*NSLOT+mb];
        float4 r1=*(const float4*)&rwl[1*NSLOT+mb];
        float4 r2=*(const float4*)&rwl[2*NSLOT+mb];
        float4 r3=*(const float4*)&rwl[3*NSLOT+mb];
        fa0+=l4.x*r0.x+l4.y*r0.y+l4.z*r0.z+l4.w*r0.w;
        fa1+=l4.x*r1.x+l4.y*r1.y+l4.z*r1.z+l4.w*r1.w;
        fa2+=l4.x*r2.x+l4.y*r2.y+l4.z*r2.z+l4.w*r2.w;
        fa3+=l4.x*r3.x+l4.y*r3.y+l4.z*r3.z+l4.w*r3.w;
        float4 t4=*(float4*)&Tr[mb];
        t4.x=c0*t4.x+wm4.x*pmn; t4.y=c1*t4.y+wm4.y*pmn;
        t4.z=c2*t4.z+wm4.z*pmn; t4.w=c3*t4.w+wm4.w*pmn;
        if (d>=0 && d<4) ((float*)&t4)[d]=0.f;
        *(float4*)&Tr[mb]=t4;
        ba0+=t4.x*r0.x+t4.y*r0.y+t4.z*r0.z+t4.w*r0.w;
        ba1+=t4.x*r1.x+t4.y*r1.y+t4.z*r1.z+t4.w*r1.w;
        ba2+=t4.x*r2.x+t4.y*r2.y+t4.z*r2.z+t4.w*r2.w;
        ba3+=t4.x*r3.x+t4.y*r3.y+t4.z*r3.z+t4.w*r3.w;
      }
      fa0=red64s(fa0); fa1=red64s(fa1); fa2=red64s(fa2); fa3=red64s(fa3);
      ba0=red64s(ba0); ba1=red64s(ba1); ba2=red64s(ba2); ba3=red64s(ba3);
      if (sub==0){
        fwdb[0*NROW+row]=fa0; fwdb[1*NROW+row]=fa1; fwdb[2*NROW+row]=fa2; fwdb[3*NROW+row]=fa3;
        bwdb[0*NROW+row]=ba0; bwdb[1*NROW+row]=ba1; bwdb[2*NROW+row]=ba2; bwdb[3*NROW+row]=ba3;
      }
    }
    { // Mem update + rc dots + wd_{t+1} (prefetched wkv) + mnorm; 1 elem/lane
      float wn=wwl[n0+row];
      float m=Mem[row*MSTR+sub];
      m = m*(1.f-wn*prs[P_ERA+sub]) + wn*prs[P_WV+sub];
      Mem[row*MSTR+sub]=m;
      float rd0=m*prs[  0+sub];
      float rd1=m*prs[ 64+sub];
      float rd2=m*prs[128+sub];
      float rd3=m*prs[192+sub];
      float ms=m*m, wd=m*wkv;
      rd0=red64s(rd0); rd1=red64s(rd1); rd2=red64s(rd2); rd3=red64s(rd3);
      ms=red64s(ms); wd=red64s(wd);
      if (sub==0){
        float mn=sqrtf(ms);
        ern[0*NROW+row]=expf(prs[256]*rd0/(prs[P_RKN+0]*mn+EPSV));
        ern[1*NROW+row]=expf(prs[257]*rd1/(prs[P_RKN+1]*mn+EPSV));
        ern[2*NROW+row]=expf(prs[258]*rd2/(prs[P_RKN+2]*mn+EPSV));
        ern[3*NROW+row]=expf(prs[259]*rd3/(prs[480]*mn+EPSV));
        stg2(qb+B_WM+2*(n0+row), wd, mn);
      }
    }
    { // alloc_{t+1} scan (usage_t written in C, synced s3), f4 loads
      int n=n0+row;
      float u_n=usagel[n], pr=1.f;
      #pragma unroll
      for (int mb=0; mb<2; mb++){
        int m0=(sub+64*mb)*4;
        float4 u4=*(const float4*)&usagel[m0];
        pr *= (u4.x<u_n || (u4.x==u_n && m0  <n)) ? u4.x : 1.f;
        pr *= (u4.y<u_n || (u4.y==u_n && m0+1<n)) ? u4.y : 1.f;
        pr *= (u4.z<u_n || (u4.z==u_n && m0+2<n)) ? u4.z : 1.f;
        pr *= (u4.w<u_n || (u4.w==u_n && m0+3<n)) ? u4.w : 1.f;
      }
      pr=red64m(pr);
      if (sub==0) stg(qb+B_ALO+n, (1.f-u_n)*pr);
    }
    __syncthreads();                                   // sync 4

    // ---- F: prec update, EN/SEP publishes ----
    if (tid<512){
      const float Sww=red[12]+red[13]+red[14]+red[15]+red[16]+red[17]+red[18]+red[19];
      precl[tid]=(1.f-Sww)*precl[tid]+wwl[tid];
    }
    if (tid<64){
      int r=tid>>4, rw_=tid&15;
      float e=ern[r*NROW+rw_];
      float nn=mcur[r*3+0]*bwdb[r*NROW+rw_] + mcur[r*3+2]*fwdb[r*NROW+rw_];
      stg2(qb+B_EN+2*(r*NSLOT+n0+rw_), e, nn);
      float v=red16s(e);
      if (rw_==0) stg(qb+B_SEP+g*4+r, v);
    }

    // ---- early arrive: drain publishes, raise flag ----
    asm volatile("s_waitcnt vmcnt(0)" ::: "memory");
    __syncthreads();
    if (tid==0) __hip_atomic_store(flg+b*512+g*16, 3u+(unsigned)t, __ATOMIC_RELAXED, __HIP_MEMORY_SCOPE_AGENT);

    // ---- parse iface_{t+1} (hidden behind peers' arrival) ----
    if (t<NTT-1){
      const float* ifc = ws + (size_t)(b*NTT+(t+1))*NIF;
      float* mnx = modesA + 12*((t+1)&1);
      if (tid<324) prs[tid]=ifc[tid];
      __syncthreads();
      if (tid<4) prs[256+tid]=softpl(prs[256+tid]);
      else if (tid==4) prs[P_WS]=softpl(ifc[324]);
      else if (tid>=8 && tid<12) prs[P_FG+(tid-8)]=sigm(ifc[453+(tid-8)]);
      else if (tid==12) prs[P_AG]=sigm(ifc[457]);
      else if (tid==13) prs[P_WG]=sigm(ifc[458]);
      else if (tid>=16 && tid<20){
        int r=tid-16;
        float x0=ifc[459+r*3],x1=ifc[460+r*3],x2=ifc[461+r*3];
        float mx=fmaxf(x0,fmaxf(x1,x2));
        float e0=expf(x0-mx),e1=expf(x1-mx),e2=expf(x2-mx),s=e0+e1+e2;
        prs[P_MOD+r*3+0]=e0/s; prs[P_MOD+r*3+1]=e1/s; prs[P_MOD+r*3+2]=e2/s;
        mnx[r*3+0]=e0/s; mnx[r*3+1]=e1/s; mnx[r*3+2]=e2/s;
      }
      else if (tid>=64 && tid<128) prs[P_ERA+(tid-64)]=sigm(ifc[325+(tid-64)]);
      else if (tid>=192 && tid<256) prs[P_WV+(tid-192)]=ifc[389+(tid-192)];
      {
        int wv=tid>>6, lane=tid&63;
        if (wv<4){
          float v = (wv==0)? prs[260+lane] : prs[(wv-1)*64+lane];
          v = red64s(v*v);
          if (lane==0) prs[P_WKN+wv]=sqrtf(v);
          if (wv==0){
            float u=prs[192+lane];
            u=red64s(u*u);
            if (lane==0) prs[480]=sqrtf(u);
          }
        }
      }
    }

    // ---- late poll ----
    if (tid<GPB){
      while (__hip_atomic_load(flg+b*512+tid*16, __ATOMIC_RELAXED, __HIP_MEMORY_SCOPE_AGENT) < 3u+(unsigned)t)
        __builtin_amdgcn_s_sleep(1);
    }
    __syncthreads();
    asm volatile("" ::: "memory");
  }

  // final barrier: partials_15 published during drain phase
  lbar(flg, b, g, 3u+NTT, tid);
  if (tid<256){
    const float* fb = ws + IFCF + ((NTT+1)&1)*PARF + b*BATF;
    float v=ldc(fb+B_RWP+(tid&31)*256+g*8+(tid>>5));
    v=red32s(v);
    if ((tid&31)==0) out[(size_t)(b*NTT+(NTT-1))*256 + g*8 + (tid>>5)] = v;
  }
}

extern "C" void kernel_launch(void* const* d_in, const int* in_sizes, int n_in,
                              void* d_out, int out_size, void* d_ws, size_t ws_size,
                              hipStream_t stream)
{
  const float* ctrl=(const float*)d_in[0];
  const float* wif =(const float*)d_in[1];
  const float* bif =(const float*)d_in[2];
  const float* mem0=(const float*)d_in[3];
  float* outp=(float*)d_out;
  unsigned* flg=(unsigned*)d_ws;
  float* wsf=(float*)((char*)d_ws+32768);

  hipMemsetAsync(d_ws, 0, 32768, stream);   // zero generation flags each launch

  void* args[]={(void*)&ctrl,(void*)&wif,(void*)&bif,(void*)&mem0,(void*)&outp,(void*)&wsf,(void*)&flg};
  hipError_t err = hipLaunchCooperativeKernel((void*)dnc_kernel, dim3(NBLK), dim3(BS), args, 0, stream);
  if (err != hipSuccess){
    // fallback: plain launch (256 blocks @ 1 block/CU on 256 CUs — co-residency holds)
    hipLaunchKernelGGL(dnc_kernel, dim3(NBLK), dim3(BS), 0, stream,
                       ctrl, wif, bif, mem0, outp, wsf, flg);
  }
}

// Round 13
// 277.685 us; speedup vs baseline: 1.2627x; 1.2627x over previous
//
#include <hip/hip_runtime.h>
#include <math.h>

// DNC MemoryAccess forward. B=8, T=16, N=512, W=64, R=4, NW=1, MODES=3, IFACE=471.
// Persistent kernel: 256 blocks (32/batch, NROW=16) x 512 threads — all 256 CUs active.
// L + LT + Mem shards in LDS; usage/prec/ww replicated. ONE relaxed flag-barrier per
// step, early-arrive/late-poll; exchange via relaxed agent atomics, one burst per step.
// This rev: L/LT/prec/Mem register PREFETCH at step top (stable since prev step) so the
// D-phase update+matvec starts from registers instead of a 12-deep ds_read chain.

#define NBATCH 8
#define GPB    32
#define NBLK   (NBATCH*GPB)
#define BS     512
#define NROW   16
#define NTT    16
#define NSLOT  512
#define WRD    64
#define RH     4
#define NIF    471
#define LSTR   520
#define MSTR   65
#define EPSV   1e-6f

// per-parity per-batch float offsets in exchange region
#define B_ALO  0            // [512] allocation
#define B_WM   512          // [512][2] (write-dot, mnorm) pairs
#define B_EN   1536         // [4*512][2] (read-content exp, m0*bwd+m2*fwd) pairs
#define B_SEP  5632         // [32][4] partial sums of ER
#define B_RWP  5760         // [32][256] read-word partials
#define BATF   13952
#define IFCF   (NBATCH*NTT*NIF)     // 60288 floats of iface
#define PARF   (NBATCH*BATF)

// prs layout (16B-aligned vector fields)
#define P_ERA 328
#define P_WV  392
#define P_WS  456
#define P_FG  457
#define P_AG  461
#define P_WG  462
#define P_MOD 464
#define P_WKN 476
#define P_RKN 477

__device__ __forceinline__ float sigm(float x){ return 1.f/(1.f+expf(-x)); }
__device__ __forceinline__ float softpl(float x){ return x>0.f ? x+log1pf(expf(-x)) : log1pf(expf(x)); }
__device__ __forceinline__ float red16s(float v){ v+=__shfl_xor(v,1,16); v+=__shfl_xor(v,2,16); v+=__shfl_xor(v,4,16); v+=__shfl_xor(v,8,16); return v; }
__device__ __forceinline__ float red32s(float v){ v+=__shfl_xor(v,1,32); v+=__shfl_xor(v,2,32); v+=__shfl_xor(v,4,32); v+=__shfl_xor(v,8,32); v+=__shfl_xor(v,16,32); return v; }
__device__ __forceinline__ float red32m(float v){ v*=__shfl_xor(v,1,32); v*=__shfl_xor(v,2,32); v*=__shfl_xor(v,4,32); v*=__shfl_xor(v,8,32); v*=__shfl_xor(v,16,32); return v; }
__device__ __forceinline__ float red64s(float v){
  v+=__shfl_xor(v,1); v+=__shfl_xor(v,2); v+=__shfl_xor(v,4);
  v+=__shfl_xor(v,8); v+=__shfl_xor(v,16); v+=__shfl_xor(v,32); return v; }

__device__ __forceinline__ void stg(float* p, float v){
  __hip_atomic_store(p, v, __ATOMIC_RELAXED, __HIP_MEMORY_SCOPE_AGENT);
}
__device__ __forceinline__ float ldc(const float* p){
  return __hip_atomic_load(p, __ATOMIC_RELAXED, __HIP_MEMORY_SCOPE_AGENT);
}
__device__ __forceinline__ void stg2(float* p, float x, float y){
  union { float2 f; unsigned long long u; } v; v.f=make_float2(x,y);
  __hip_atomic_store((unsigned long long*)p, v.u, __ATOMIC_RELAXED, __HIP_MEMORY_SCOPE_AGENT);
}
__device__ __forceinline__ float2 ldc2(const float* p){
  union { float2 f; unsigned long long u; } v;
  v.u=__hip_atomic_load((const unsigned long long*)p, __ATOMIC_RELAXED, __HIP_MEMORY_SCOPE_AGENT);
  return v.f;
}

// flag slot: flg[b*512 + g*16] -- each block's flag in its own 64B line
__device__ __forceinline__ void lbar(unsigned* flg, int b, int g, unsigned gen, int tid){
  asm volatile("s_waitcnt vmcnt(0)" ::: "memory");
  __syncthreads();
  if (tid==0) __hip_atomic_store(flg+b*512+g*16, gen, __ATOMIC_RELAXED, __HIP_MEMORY_SCOPE_AGENT);
  if (tid<GPB){
    while (__hip_atomic_load(flg+b*512+tid*16, __ATOMIC_RELAXED, __HIP_MEMORY_SCOPE_AGENT) < gen)
      __builtin_amdgcn_s_sleep(1);
  }
  __syncthreads();
  asm volatile("" ::: "memory");
}

__global__ void __launch_bounds__(BS)
dnc_kernel(const float* __restrict__ ctrl, const float* __restrict__ wif,
           const float* __restrict__ bif, const float* __restrict__ mem0,
           float* __restrict__ out, float* __restrict__ ws, unsigned* __restrict__ flg)
{
  const int tid = threadIdx.x;
  const int bid = blockIdx.x;
  const int b   = bid & 7;
  const int g   = bid >> 3;        // 0..31
  const int n0  = g * NROW;

  __shared__ __align__(16) float L  [NROW*LSTR];
  __shared__ __align__(16) float LT [NROW*LSTR];
  __shared__ __align__(16) float Mem[NROW*MSTR];
  __shared__ __align__(16) float rwl[RH*NSLOT];
  __shared__ __align__(16) float wwl[NSLOT];
  __shared__ __align__(16) float usagel[NSLOT];
  __shared__ __align__(16) float precl[NSLOT];
  __shared__ __align__(16) float prs[488];
  __shared__ __align__(16) float aux[248];
  float* ern    = aux;        // [4][16]
  float* fwdb   = aux+64;     // [4][16]
  float* bwdb   = aux+128;    // [4][16]
  float* modesA = aux+192;    // [2][12] parity-banked
  float* red    = aux+216;    // [32]

  // ---------------- init ----------------
  for (int i=tid; i<NROW*LSTR; i+=BS){ L[i]=0.f; LT[i]=0.f; }
  for (int i=tid; i<NROW*WRD; i+=BS){
    int r=i>>6, k=i&63;
    Mem[r*MSTR+k] = mem0[(size_t)(b*NSLOT + n0 + r)*WRD + k];
  }
  if (tid<NSLOT){ usagel[tid]=0.f; precl[tid]=0.f; }
  if (g < NTT){ // iface GEMM: blocks g<16 compute iface row (b, t=g)
    float* ctrlrow = rwl;
    const float* crow = ctrl + (size_t)(b*NTT+g)*1024;
    for (int i=tid;i<1024;i+=BS) ctrlrow[i]=crow[i];
    __syncthreads();
    if (tid<NIF){
      int j=tid;
      float a0=0.f,a1=0.f,a2=0.f,a3=0.f;
      const float* wp = wif + j;
      for (int c=0;c<1024;c+=4){
        a0 += ctrlrow[c+0]*wp[(size_t)(c+0)*NIF];
        a1 += ctrlrow[c+1]*wp[(size_t)(c+1)*NIF];
        a2 += ctrlrow[c+2]*wp[(size_t)(c+2)*NIF];
        a3 += ctrlrow[c+3]*wp[(size_t)(c+3)*NIF];
      }
      ws[(size_t)(b*NTT+g)*NIF + j] = ((a0+a1)+(a2+a3)) + bif[j];
    }
  }
  __syncthreads();
  for (int i=tid;i<RH*NSLOT;i+=BS) rwl[i]=0.f;

  // heavy barrier (gen 1): makes plain-stored iface visible once
  __syncthreads();
  __builtin_amdgcn_fence(__ATOMIC_RELEASE, "agent");
  if (tid==0) __hip_atomic_store(flg+b*512+g*16, 1u, __ATOMIC_RELAXED, __HIP_MEMORY_SCOPE_AGENT);
  if (tid<GPB){
    while (__hip_atomic_load(flg+b*512+tid*16, __ATOMIC_RELAXED, __HIP_MEMORY_SCOPE_AGENT) < 1u)
      __builtin_amdgcn_s_sleep(1);
  }
  __syncthreads();
  __builtin_amdgcn_fence(__ATOMIC_ACQUIRE, "agent");

  // init publish (for step 0) into parity buffer 0
  {
    float* qb = ws + IFCF + 0*PARF + b*BATF;
    const float* ifc0 = ws + (size_t)(b*NTT+0)*NIF;
    {
      int row=tid>>5, sub=tid&31;
      float wd=0.f, ms=0.f;
      #pragma unroll
      for (int j=0;j<2;j++){
        int k=sub*2+j; float m=Mem[row*MSTR+k];
        wd += m*ifc0[260+k]; ms += m*m;
      }
      wd=red32s(wd); ms=red32s(ms);
      if (sub==0) stg2(qb+B_WM+2*(n0+row), wd, sqrtf(ms));
    }
    {
      int row=tid>>5, sub=tid&31, n=n0+row;
      float u_n=usagel[n], pr=1.f;
      for (int m=sub;m<NSLOT;m+=32){
        float um=usagel[m];
        if (um<u_n || (um==u_n && m<n)) pr*=um;
      }
      pr=red32m(pr);
      if (sub==0) stg(qb+B_ALO+n, (1.f-u_n)*pr);
    }
  }
  // parse iface_0 into prs + modesA bank 0
  {
    const float* ifc = ws + (size_t)(b*NTT+0)*NIF;
    if (tid<324) prs[tid]=ifc[tid];
    __syncthreads();
    if (tid<4) prs[256+tid]=softpl(prs[256+tid]);
    else if (tid==4) prs[P_WS]=softpl(ifc[324]);
    else if (tid>=8 && tid<12) prs[P_FG+(tid-8)]=sigm(ifc[453+(tid-8)]);
    else if (tid==12) prs[P_AG]=sigm(ifc[457]);
    else if (tid==13) prs[P_WG]=sigm(ifc[458]);
    else if (tid>=16 && tid<20){
      int r=tid-16;
      float x0=ifc[459+r*3],x1=ifc[460+r*3],x2=ifc[461+r*3];
      float mx=fmaxf(x0,fmaxf(x1,x2));
      float e0=expf(x0-mx),e1=expf(x1-mx),e2=expf(x2-mx),s=e0+e1+e2;
      prs[P_MOD+r*3+0]=e0/s; prs[P_MOD+r*3+1]=e1/s; prs[P_MOD+r*3+2]=e2/s;
      modesA[r*3+0]=e0/s; modesA[r*3+1]=e1/s; modesA[r*3+2]=e2/s;
    }
    else if (tid>=64 && tid<128) prs[P_ERA+(tid-64)]=sigm(ifc[325+(tid-64)]);
    else if (tid>=192 && tid<256) prs[P_WV+(tid-192)]=ifc[389+(tid-192)];
    {
      int wv=tid>>6, lane=tid&63;
      if (wv<4){
        float v = (wv==0)? prs[260+lane] : prs[(wv-1)*64+lane];
        v = red64s(v*v);
        if (lane==0) prs[P_WKN+wv]=sqrtf(v);
        if (wv==0){
          float u=prs[192+lane];
          u=red64s(u*u);
          if (lane==0) prs[480]=sqrtf(u);
        }
      }
    }
  }
  lbar(flg, b, g, 2u, tid);

  // ---------------- time loop (t==NTT is the drain pseudo-step) ----------------
  for (int t=0; t<=NTT; t++){
    const float* pb = ws + IFCF + (t&1)*PARF + b*BATF;
    float*       qb = ws + IFCF + ((t+1)&1)*PARF + b*BATF;
    float* mprev = modesA + 12*((t+1)&1);
    float* mcur  = modesA + 12*(t&1);
    const int row = tid>>5, sub = tid&31;

    // ---- burst: ALL exchange loads + next-step write-key prefetch ----
    float2 en[4]; float2 sep2=make_float2(1.f,1.f); float rwpv=0.f;
    float2 wm=make_float2(0.f,1.f); float al=0.f;
    float2 wk2=make_float2(0.f,0.f);
    if (t>0){
      #pragma unroll
      for (int i=0;i<4;i++) en[i]=ldc2(pb+B_EN+2*(tid+BS*i));
      if (tid<64){ int gp=tid>>1, c=tid&1; sep2=ldc2(pb+B_SEP+gp*4+c*2); }
      if (t>=2 && tid<256) rwpv=ldc(pb+B_RWP+(tid&31)*256+g*8+(tid>>5));
    }
    if (t<NTT){
      wm=ldc2(pb+B_WM+2*tid);
      al=ldc(pb+B_ALO+tid);
    }
    if (t<NTT-1){
      const float* ifn = ws + (size_t)(b*NTT+(t+1))*NIF;
      wk2 = *(const float2*)(ifn+260+sub*2);
    }

    // ---- prefetch L/LT/prec/Mem into regs (stable since previous step's writes) ----
    float4 pl[4], pt[4], pp[4];
    float2 pmem; float ppmn;
    {
      const float* Lr=&L[row*LSTR];
      const float* Tr=&LT[row*LSTR];
      #pragma unroll
      for (int jj=0;jj<4;jj++){
        int mb=(sub+32*jj)*4;
        pl[jj]=*(const float4*)&Lr[mb];
        pt[jj]=*(const float4*)&Tr[mb];
        pp[jj]=*(const float4*)&precl[mb];
      }
      pmem=*(const float2*)&Mem[row*MSTR+sub*2];
      ppmn=precl[n0+row];
    }

    // ---- A: ww-exp (regs), Se reduce (float2 over 32 groups) ----
    float ewv=0.f;
    if (t<NTT){
      ewv=expf(prs[P_WS]*wm.x/(prs[P_WKN]*wm.y+EPSV));
      wwl[tid]=ewv;
    }
    if (t>0 && tid<64){
      float vx=sep2.x, vy=sep2.y;
      vx+=__shfl_xor(vx,2); vy+=__shfl_xor(vy,2);
      vx+=__shfl_xor(vx,4); vy+=__shfl_xor(vy,4);
      vx+=__shfl_xor(vx,8); vy+=__shfl_xor(vy,8);
      vx+=__shfl_xor(vx,16); vy+=__shfl_xor(vy,16);
      vx+=__shfl_xor(vx,32); vy+=__shfl_xor(vy,32);
      if (tid<2){ red[tid*2]=vx; red[tid*2+1]=vy; }   // Se[0..3]
    }
    __syncthreads();                                   // sync 1

    // ---- B: rwl build (+psi in regs), Sw partials ----
    float psi=1.f;
    if (t>0){
      float rwv[4];
      #pragma unroll
      for (int i=0;i<4;i++){
        rwv[i] = en[i].y + mprev[i*3+1]*en[i].x/red[i];
        rwl[i*NSLOT+tid] = rwv[i];
      }
      psi=(1.f-prs[P_FG+0]*rwv[0])*(1.f-prs[P_FG+1]*rwv[1])
         *(1.f-prs[P_FG+2]*rwv[2])*(1.f-prs[P_FG+3]*rwv[3]);
    }
    if (t<NTT){ float v=red64s(ewv); if ((tid&63)==0) red[4+(tid>>6)]=v; }
    __syncthreads();                                   // sync 2

    // ---- C: RWP (t-1), out drain (t-2), ww final + usage + Sww partials ----
    if (t>0 && tid<256){
      int r=tid>>6, k=tid&63;
      float a=0.f;
      #pragma unroll
      for (int rr=0;rr<4;rr++){
        float4 rv=*(const float4*)&rwl[r*NSLOT+n0+rr*4];
        a += rv.x*Mem[(rr*4+0)*MSTR+k] + rv.y*Mem[(rr*4+1)*MSTR+k]
           + rv.z*Mem[(rr*4+2)*MSTR+k] + rv.w*Mem[(rr*4+3)*MSTR+k];
      }
      stg(qb+B_RWP+g*256+tid, a);
    }
    if (t>=2 && tid<256){
      float s=red32s(rwpv);
      if ((tid&31)==0) out[(size_t)(b*NTT+(t-2))*256 + g*8 + (tid>>5)] = s;
    }
    if (t==NTT) break;
    float wwv;
    {
      const float Sw=red[4]+red[5]+red[6]+red[7]+red[8]+red[9]+red[10]+red[11];
      wwv=prs[P_WG]*(prs[P_AG]*al+(1.f-prs[P_AG])*ewv/Sw);
      wwl[tid]=wwv;
      usagel[tid]=(usagel[tid]+wwv-usagel[tid]*wwv)*psi;
      float v=red64s(wwv);
      if ((tid&63)==0) red[12+(tid>>6)]=v;
    }
    __syncthreads();                                   // sync 3

    // ---- D: fused L/LT update + fwd/bwd (from prefetched regs); Mem update + rc +
    //         WM publish; alloc scan ----
    {
      float wn =wwl[n0+row];
      float pmn=ppmn;
      float* Lr = &L[row*LSTR];
      float* Tr = &LT[row*LSTR];
      float fa0=0.f,fa1=0.f,fa2=0.f,fa3=0.f, ba0=0.f,ba1=0.f,ba2=0.f,ba3=0.f;
      #pragma unroll
      for (int jj=0;jj<4;jj++){
        int mb=(sub+32*jj)*4;
        float4 wm4=*(float4*)&wwl[mb];
        float4 pm4=pp[jj];
        float c0=1.f-wn-wm4.x, c1=1.f-wn-wm4.y, c2=1.f-wn-wm4.z, c3=1.f-wn-wm4.w;
        int d=(n0+row)-mb;
        float4 l4=pl[jj];
        l4.x=c0*l4.x+wn*pm4.x; l4.y=c1*l4.y+wn*pm4.y;
        l4.z=c2*l4.z+wn*pm4.z; l4.w=c3*l4.w+wn*pm4.w;
        if (d>=0 && d<4) ((float*)&l4)[d]=0.f;
        *(float4*)&Lr[mb]=l4;
        float4 r0=*(const float4*)&rwl[0*NSLOT+mb];
        float4 r1=*(const float4*)&rwl[1*NSLOT+mb];
        float4 r2=*(const float4*)&rwl[2*NSLOT+mb];
        float4 r3=*(const float4*)&rwl[3*NSLOT+mb];
        fa0+=l4.x*r0.x+l4.y*r0.y+l4.z*r0.z+l4.w*r0.w;
        fa1+=l4.x*r1.x+l4.y*r1.y+l4.z*r1.z+l4.w*r1.w;
        fa2+=l4.x*r2.x+l4.y*r2.y+l4.z*r2.z+l4.w*r2.w;
        fa3+=l4.x*r3.x+l4.y*r3.y+l4.z*r3.z+l4.w*r3.w;
        float4 t4=pt[jj];
        t4.x=c0*t4.x+wm4.x*pmn; t4.y=c1*t4.y+wm4.y*pmn;
        t4.z=c2*t4.z+wm4.z*pmn; t4.w=c3*t4.w+wm4.w*pmn;
        if (d>=0 && d<4) ((float*)&t4)[d]=0.f;
        *(float4*)&Tr[mb]=t4;
        ba0+=t4.x*r0.x+t4.y*r0.y+t4.z*r0.z+t4.w*r0.w;
        ba1+=t4.x*r1.x+t4.y*r1.y+t4.z*r1.z+t4.w*r1.w;
        ba2+=t4.x*r2.x+t4.y*r2.y+t4.z*r2.z+t4.w*r2.w;
        ba3+=t4.x*r3.x+t4.y*r3.y+t4.z*r3.z+t4.w*r3.w;
      }
      fa0=red32s(fa0); fa1=red32s(fa1); fa2=red32s(fa2); fa3=red32s(fa3);
      ba0=red32s(ba0); ba1=red32s(ba1); ba2=red32s(ba2); ba3=red32s(ba3);
      if (sub==0){
        fwdb[0*NROW+row]=fa0; fwdb[1*NROW+row]=fa1; fwdb[2*NROW+row]=fa2; fwdb[3*NROW+row]=fa3;
        bwdb[0*NROW+row]=ba0; bwdb[1*NROW+row]=ba1; bwdb[2*NROW+row]=ba2; bwdb[3*NROW+row]=ba3;
      }
    }
    { // Mem update + rc dots + wd_{t+1} (prefetched wk2) + mnorm; f2 prs reads
      float wn=wwl[n0+row];
      float2 er =*(float2*)&prs[P_ERA+sub*2];
      float2 wvv=*(float2*)&prs[P_WV +sub*2];
      float m0=pmem.x, m1=pmem.y;
      m0=m0*(1.f-wn*er.x)+wn*wvv.x; m1=m1*(1.f-wn*er.y)+wn*wvv.y;
      Mem[row*MSTR+sub*2+0]=m0; Mem[row*MSTR+sub*2+1]=m1;
      float2 k0=*(float2*)&prs[  0+sub*2];
      float2 k1=*(float2*)&prs[ 64+sub*2];
      float2 k2=*(float2*)&prs[128+sub*2];
      float2 k3=*(float2*)&prs[192+sub*2];
      float rd0=m0*k0.x+m1*k0.y;
      float rd1=m0*k1.x+m1*k1.y;
      float rd2=m0*k2.x+m1*k2.y;
      float rd3=m0*k3.x+m1*k3.y;
      float ms=m0*m0+m1*m1;
      float wd=m0*wk2.x+m1*wk2.y;
      rd0=red32s(rd0); rd1=red32s(rd1); rd2=red32s(rd2); rd3=red32s(rd3);
      ms=red32s(ms); wd=red32s(wd);
      if (sub==0){
        float mn=sqrtf(ms);
        ern[0*NROW+row]=expf(prs[256]*rd0/(prs[P_RKN+0]*mn+EPSV));
        ern[1*NROW+row]=expf(prs[257]*rd1/(prs[P_RKN+1]*mn+EPSV));
        ern[2*NROW+row]=expf(prs[258]*rd2/(prs[P_RKN+2]*mn+EPSV));
        ern[3*NROW+row]=expf(prs[259]*rd3/(prs[480]*mn+EPSV));
        stg2(qb+B_WM+2*(n0+row), wd, mn);
      }
    }
    { // alloc_{t+1} scan (usage_t written in C, synced s3), f4 loads
      int n=n0+row;
      float u_n=usagel[n], pr=1.f;
      #pragma unroll
      for (int mb=0; mb<4; mb++){
        int m0=(sub+32*mb)*4;
        float4 u4=*(const float4*)&usagel[m0];
        pr *= (u4.x<u_n || (u4.x==u_n && m0  <n)) ? u4.x : 1.f;
        pr *= (u4.y<u_n || (u4.y==u_n && m0+1<n)) ? u4.y : 1.f;
        pr *= (u4.z<u_n || (u4.z==u_n && m0+2<n)) ? u4.z : 1.f;
        pr *= (u4.w<u_n || (u4.w==u_n && m0+3<n)) ? u4.w : 1.f;
      }
      pr=red32m(pr);
      if (sub==0) stg(qb+B_ALO+n, (1.f-u_n)*pr);
    }
    __syncthreads();                                   // sync 4

    // ---- F: prec update, EN/SEP publishes ----
    {
      const float Sww=red[12]+red[13]+red[14]+red[15]+red[16]+red[17]+red[18]+red[19];
      precl[tid]=(1.f-Sww)*precl[tid]+wwl[tid];
    }
    if (tid<64){
      int r=tid>>4, rw_=tid&15;
      float e=ern[r*NROW+rw_];
      float nn=mcur[r*3+0]*bwdb[r*NROW+rw_] + mcur[r*3+2]*fwdb[r*NROW+rw_];
      stg2(qb+B_EN+2*(r*NSLOT+n0+rw_), e, nn);
      float v=e;
      v+=__shfl_xor(v,1,16); v+=__shfl_xor(v,2,16);
      v+=__shfl_xor(v,4,16); v+=__shfl_xor(v,8,16);
      if (rw_==0) stg(qb+B_SEP+g*4+r, v);
    }

    // ---- early arrive: drain publishes, raise flag ----
    asm volatile("s_waitcnt vmcnt(0)" ::: "memory");
    __syncthreads();
    if (tid==0) __hip_atomic_store(flg+b*512+g*16, 3u+(unsigned)t, __ATOMIC_RELAXED, __HIP_MEMORY_SCOPE_AGENT);

    // ---- parse iface_{t+1} (hidden behind peers' arrival) ----
    if (t<NTT-1){
      const float* ifc = ws + (size_t)(b*NTT+(t+1))*NIF;
      float* mnx = modesA + 12*((t+1)&1);
      if (tid<324) prs[tid]=ifc[tid];
      __syncthreads();
      if (tid<4) prs[256+tid]=softpl(prs[256+tid]);
      else if (tid==4) prs[P_WS]=softpl(ifc[324]);
      else if (tid>=8 && tid<12) prs[P_FG+(tid-8)]=sigm(ifc[453+(tid-8)]);
      else if (tid==12) prs[P_AG]=sigm(ifc[457]);
      else if (tid==13) prs[P_WG]=sigm(ifc[458]);
      else if (tid>=16 && tid<20){
        int r=tid-16;
        float x0=ifc[459+r*3],x1=ifc[460+r*3],x2=ifc[461+r*3];
        float mx=fmaxf(x0,fmaxf(x1,x2));
        float e0=expf(x0-mx),e1=expf(x1-mx),e2=expf(x2-mx),s=e0+e1+e2;
        prs[P_MOD+r*3+0]=e0/s; prs[P_MOD+r*3+1]=e1/s; prs[P_MOD+r*3+2]=e2/s;
        mnx[r*3+0]=e0/s; mnx[r*3+1]=e1/s; mnx[r*3+2]=e2/s;
      }
      else if (tid>=64 && tid<128) prs[P_ERA+(tid-64)]=sigm(ifc[325+(tid-64)]);
      else if (tid>=192 && tid<256) prs[P_WV+(tid-192)]=ifc[389+(tid-192)];
      {
        int wv=tid>>6, lane=tid&63;
        if (wv<4){
          float v = (wv==0)? prs[260+lane] : prs[(wv-1)*64+lane];
          v = red64s(v*v);
          if (lane==0) prs[P_WKN+wv]=sqrtf(v);
          if (wv==0){
            float u=prs[192+lane];
            u=red64s(u*u);
            if (lane==0) prs[480]=sqrtf(u);
          }
        }
      }
    }

    // ---- late poll ----
    if (tid<GPB){
      while (__hip_atomic_load(flg+b*512+tid*16, __ATOMIC_RELAXED, __HIP_MEMORY_SCOPE_AGENT) < 3u+(unsigned)t)
        __builtin_amdgcn_s_sleep(1);
    }
    __syncthreads();
    asm volatile("" ::: "memory");
  }

  // final barrier: partials_15 published during drain phase
  lbar(flg, b, g, 3u+NTT, tid);
  if (tid<256){
    const float* fb = ws + IFCF + ((NTT+1)&1)*PARF + b*BATF;
    float v=ldc(fb+B_RWP+(tid&31)*256+g*8+(tid>>5));
    v=red32s(v);
    if ((tid&31)==0) out[(size_t)(b*NTT+(NTT-1))*256 + g*8 + (tid>>5)] = v;
  }
}

extern "C" void kernel_launch(void* const* d_in, const int* in_sizes, int n_in,
                              void* d_out, int out_size, void* d_ws, size_t ws_size,
                              hipStream_t stream)
{
  const float* ctrl=(const float*)d_in[0];
  const float* wif =(const float*)d_in[1];
  const float* bif =(const float*)d_in[2];
  const float* mem0=(const float*)d_in[3];
  float* outp=(float*)d_out;
  unsigned* flg=(unsigned*)d_ws;
  float* wsf=(float*)((char*)d_ws+32768);

  hipMemsetAsync(d_ws, 0, 32768, stream);   // zero generation flags each launch

  void* args[]={(void*)&ctrl,(void*)&wif,(void*)&bif,(void*)&mem0,(void*)&outp,(void*)&wsf,(void*)&flg};
  hipError_t err = hipLaunchCooperativeKernel((void*)dnc_kernel, dim3(NBLK), dim3(BS), args, 0, stream);
  if (err != hipSuccess){
    // fallback: plain launch (256 blocks @ 1 block/CU on 256 CUs — co-residency holds)
    hipLaunchKernelGGL(dnc_kernel, dim3(NBLK), dim3(BS), 0, stream,
                       ctrl, wif, bif, mem0, outp, wsf, flg);
  }
}

// Round 14
// 265.555 us; speedup vs baseline: 1.3203x; 1.0457x over previous
//
#include <hip/hip_runtime.h>
#include <math.h>

// DNC MemoryAccess forward. B=8, T=16, N=512, W=64, R=4, NW=1, MODES=3, IFACE=471.
// Persistent kernel: 256 blocks (32/batch, NROW=16) x 512 threads — all 256 CUs active.
// L + LT + Mem shards in LDS; usage/prec/ww replicated. ONE relaxed flag-barrier per
// step, early-arrive/late-poll; exchange via relaxed agent atomics, one burst per step.
// (R10 structure restored — proven 267us; R12/R13 scale-up/prefetch both spilled.)
// Micro-opt: red[0..3] hold 1/Se so phase B multiplies instead of divides.

#define NBATCH 8
#define GPB    32
#define NBLK   (NBATCH*GPB)
#define BS     512
#define NROW   16
#define NTT    16
#define NSLOT  512
#define WRD    64
#define RH     4
#define NIF    471
#define LSTR   520
#define MSTR   65
#define EPSV   1e-6f

// per-parity per-batch float offsets in exchange region
#define B_ALO  0            // [512] allocation
#define B_WM   512          // [512][2] (write-dot, mnorm) pairs
#define B_EN   1536         // [4*512][2] (read-content exp, m0*bwd+m2*fwd) pairs
#define B_SEP  5632         // [32][4] partial sums of ER
#define B_RWP  5760         // [32][256] read-word partials
#define BATF   13952
#define IFCF   (NBATCH*NTT*NIF)     // 60288 floats of iface
#define PARF   (NBATCH*BATF)

// prs layout (16B-aligned vector fields)
#define P_ERA 328
#define P_WV  392
#define P_WS  456
#define P_FG  457
#define P_AG  461
#define P_WG  462
#define P_MOD 464
#define P_WKN 476
#define P_RKN 477

__device__ __forceinline__ float sigm(float x){ return 1.f/(1.f+expf(-x)); }
__device__ __forceinline__ float softpl(float x){ return x>0.f ? x+log1pf(expf(-x)) : log1pf(expf(x)); }
__device__ __forceinline__ float red16s(float v){ v+=__shfl_xor(v,1,16); v+=__shfl_xor(v,2,16); v+=__shfl_xor(v,4,16); v+=__shfl_xor(v,8,16); return v; }
__device__ __forceinline__ float red32s(float v){ v+=__shfl_xor(v,1,32); v+=__shfl_xor(v,2,32); v+=__shfl_xor(v,4,32); v+=__shfl_xor(v,8,32); v+=__shfl_xor(v,16,32); return v; }
__device__ __forceinline__ float red32m(float v){ v*=__shfl_xor(v,1,32); v*=__shfl_xor(v,2,32); v*=__shfl_xor(v,4,32); v*=__shfl_xor(v,8,32); v*=__shfl_xor(v,16,32); return v; }
__device__ __forceinline__ float red64s(float v){
  v+=__shfl_xor(v,1); v+=__shfl_xor(v,2); v+=__shfl_xor(v,4);
  v+=__shfl_xor(v,8); v+=__shfl_xor(v,16); v+=__shfl_xor(v,32); return v; }

__device__ __forceinline__ void stg(float* p, float v){
  __hip_atomic_store(p, v, __ATOMIC_RELAXED, __HIP_MEMORY_SCOPE_AGENT);
}
__device__ __forceinline__ float ldc(const float* p){
  return __hip_atomic_load(p, __ATOMIC_RELAXED, __HIP_MEMORY_SCOPE_AGENT);
}
__device__ __forceinline__ void stg2(float* p, float x, float y){
  union { float2 f; unsigned long long u; } v; v.f=make_float2(x,y);
  __hip_atomic_store((unsigned long long*)p, v.u, __ATOMIC_RELAXED, __HIP_MEMORY_SCOPE_AGENT);
}
__device__ __forceinline__ float2 ldc2(const float* p){
  union { float2 f; unsigned long long u; } v;
  v.u=__hip_atomic_load((const unsigned long long*)p, __ATOMIC_RELAXED, __HIP_MEMORY_SCOPE_AGENT);
  return v.f;
}

// flag slot: flg[b*512 + g*16] -- each block's flag in its own 64B line
__device__ __forceinline__ void lbar(unsigned* flg, int b, int g, unsigned gen, int tid){
  asm volatile("s_waitcnt vmcnt(0)" ::: "memory");
  __syncthreads();
  if (tid==0) __hip_atomic_store(flg+b*512+g*16, gen, __ATOMIC_RELAXED, __HIP_MEMORY_SCOPE_AGENT);
  if (tid<GPB){
    while (__hip_atomic_load(flg+b*512+tid*16, __ATOMIC_RELAXED, __HIP_MEMORY_SCOPE_AGENT) < gen)
      __builtin_amdgcn_s_sleep(1);
  }
  __syncthreads();
  asm volatile("" ::: "memory");
}

__global__ void __launch_bounds__(BS)
dnc_kernel(const float* __restrict__ ctrl, const float* __restrict__ wif,
           const float* __restrict__ bif, const float* __restrict__ mem0,
           float* __restrict__ out, float* __restrict__ ws, unsigned* __restrict__ flg)
{
  const int tid = threadIdx.x;
  const int bid = blockIdx.x;
  const int b   = bid & 7;
  const int g   = bid >> 3;        // 0..31
  const int n0  = g * NROW;

  __shared__ __align__(16) float L  [NROW*LSTR];
  __shared__ __align__(16) float LT [NROW*LSTR];
  __shared__ __align__(16) float Mem[NROW*MSTR];
  __shared__ __align__(16) float rwl[RH*NSLOT];
  __shared__ __align__(16) float wwl[NSLOT];
  __shared__ __align__(16) float usagel[NSLOT];
  __shared__ __align__(16) float precl[NSLOT];
  __shared__ __align__(16) float prs[488];
  __shared__ __align__(16) float aux[248];
  float* ern    = aux;        // [4][16]
  float* fwdb   = aux+64;     // [4][16]
  float* bwdb   = aux+128;    // [4][16]
  float* modesA = aux+192;    // [2][12] parity-banked
  float* red    = aux+216;    // [32]

  // ---------------- init ----------------
  for (int i=tid; i<NROW*LSTR; i+=BS){ L[i]=0.f; LT[i]=0.f; }
  for (int i=tid; i<NROW*WRD; i+=BS){
    int r=i>>6, k=i&63;
    Mem[r*MSTR+k] = mem0[(size_t)(b*NSLOT + n0 + r)*WRD + k];
  }
  if (tid<NSLOT){ usagel[tid]=0.f; precl[tid]=0.f; }
  if (g < NTT){ // iface GEMM: blocks g<16 compute iface row (b, t=g)
    float* ctrlrow = rwl;
    const float* crow = ctrl + (size_t)(b*NTT+g)*1024;
    for (int i=tid;i<1024;i+=BS) ctrlrow[i]=crow[i];
    __syncthreads();
    if (tid<NIF){
      int j=tid;
      float a0=0.f,a1=0.f,a2=0.f,a3=0.f;
      const float* wp = wif + j;
      for (int c=0;c<1024;c+=4){
        a0 += ctrlrow[c+0]*wp[(size_t)(c+0)*NIF];
        a1 += ctrlrow[c+1]*wp[(size_t)(c+1)*NIF];
        a2 += ctrlrow[c+2]*wp[(size_t)(c+2)*NIF];
        a3 += ctrlrow[c+3]*wp[(size_t)(c+3)*NIF];
      }
      ws[(size_t)(b*NTT+g)*NIF + j] = ((a0+a1)+(a2+a3)) + bif[j];
    }
  }
  __syncthreads();
  for (int i=tid;i<RH*NSLOT;i+=BS) rwl[i]=0.f;

  // heavy barrier (gen 1): makes plain-stored iface visible once
  __syncthreads();
  __builtin_amdgcn_fence(__ATOMIC_RELEASE, "agent");
  if (tid==0) __hip_atomic_store(flg+b*512+g*16, 1u, __ATOMIC_RELAXED, __HIP_MEMORY_SCOPE_AGENT);
  if (tid<GPB){
    while (__hip_atomic_load(flg+b*512+tid*16, __ATOMIC_RELAXED, __HIP_MEMORY_SCOPE_AGENT) < 1u)
      __builtin_amdgcn_s_sleep(1);
  }
  __syncthreads();
  __builtin_amdgcn_fence(__ATOMIC_ACQUIRE, "agent");

  // init publish (for step 0) into parity buffer 0
  {
    float* qb = ws + IFCF + 0*PARF + b*BATF;
    const float* ifc0 = ws + (size_t)(b*NTT+0)*NIF;
    {
      int row=tid>>5, sub=tid&31;
      float wd=0.f, ms=0.f;
      #pragma unroll
      for (int j=0;j<2;j++){
        int k=sub*2+j; float m=Mem[row*MSTR+k];
        wd += m*ifc0[260+k]; ms += m*m;
      }
      wd=red32s(wd); ms=red32s(ms);
      if (sub==0) stg2(qb+B_WM+2*(n0+row), wd, sqrtf(ms));
    }
    {
      int row=tid>>5, sub=tid&31, n=n0+row;
      float u_n=usagel[n], pr=1.f;
      for (int m=sub;m<NSLOT;m+=32){
        float um=usagel[m];
        if (um<u_n || (um==u_n && m<n)) pr*=um;
      }
      pr=red32m(pr);
      if (sub==0) stg(qb+B_ALO+n, (1.f-u_n)*pr);
    }
  }
  // parse iface_0 into prs + modesA bank 0
  {
    const float* ifc = ws + (size_t)(b*NTT+0)*NIF;
    if (tid<324) prs[tid]=ifc[tid];
    __syncthreads();
    if (tid<4) prs[256+tid]=softpl(prs[256+tid]);
    else if (tid==4) prs[P_WS]=softpl(ifc[324]);
    else if (tid>=8 && tid<12) prs[P_FG+(tid-8)]=sigm(ifc[453+(tid-8)]);
    else if (tid==12) prs[P_AG]=sigm(ifc[457]);
    else if (tid==13) prs[P_WG]=sigm(ifc[458]);
    else if (tid>=16 && tid<20){
      int r=tid-16;
      float x0=ifc[459+r*3],x1=ifc[460+r*3],x2=ifc[461+r*3];
      float mx=fmaxf(x0,fmaxf(x1,x2));
      float e0=expf(x0-mx),e1=expf(x1-mx),e2=expf(x2-mx),s=e0+e1+e2;
      prs[P_MOD+r*3+0]=e0/s; prs[P_MOD+r*3+1]=e1/s; prs[P_MOD+r*3+2]=e2/s;
      modesA[r*3+0]=e0/s; modesA[r*3+1]=e1/s; modesA[r*3+2]=e2/s;
    }
    else if (tid>=64 && tid<128) prs[P_ERA+(tid-64)]=sigm(ifc[325+(tid-64)]);
    else if (tid>=192 && tid<256) prs[P_WV+(tid-192)]=ifc[389+(tid-192)];
    {
      int wv=tid>>6, lane=tid&63;
      if (wv<4){
        float v = (wv==0)? prs[260+lane] : prs[(wv-1)*64+lane];
        v = red64s(v*v);
        if (lane==0) prs[P_WKN+wv]=sqrtf(v);
        if (wv==0){
          float u=prs[192+lane];
          u=red64s(u*u);
          if (lane==0) prs[480]=sqrtf(u);
        }
      }
    }
  }
  lbar(flg, b, g, 2u, tid);

  // ---------------- time loop (t==NTT is the drain pseudo-step) ----------------
  for (int t=0; t<=NTT; t++){
    const float* pb = ws + IFCF + (t&1)*PARF + b*BATF;
    float*       qb = ws + IFCF + ((t+1)&1)*PARF + b*BATF;
    float* mprev = modesA + 12*((t+1)&1);
    float* mcur  = modesA + 12*(t&1);
    const int row = tid>>5, sub = tid&31;

    // ---- burst: ALL exchange loads + next-step write-key prefetch ----
    float2 en[4]; float2 sep2=make_float2(1.f,1.f); float rwpv=0.f;
    float2 wm=make_float2(0.f,1.f); float al=0.f;
    float2 wk2=make_float2(0.f,0.f);
    if (t>0){
      #pragma unroll
      for (int i=0;i<4;i++) en[i]=ldc2(pb+B_EN+2*(tid+BS*i));
      if (tid<64){ int gp=tid>>1, c=tid&1; sep2=ldc2(pb+B_SEP+gp*4+c*2); }
      if (t>=2 && tid<256) rwpv=ldc(pb+B_RWP+(tid&31)*256+g*8+(tid>>5));
    }
    if (t<NTT){
      wm=ldc2(pb+B_WM+2*tid);
      al=ldc(pb+B_ALO+tid);
    }
    if (t<NTT-1){
      const float* ifn = ws + (size_t)(b*NTT+(t+1))*NIF;
      wk2 = *(const float2*)(ifn+260+sub*2);
    }

    // ---- A: ww-exp (regs), 1/Se reduce (float2 over 32 groups) ----
    float ewv=0.f;
    if (t<NTT){
      ewv=expf(prs[P_WS]*wm.x/(prs[P_WKN]*wm.y+EPSV));
      wwl[tid]=ewv;
    }
    if (t>0 && tid<64){
      float vx=sep2.x, vy=sep2.y;
      vx+=__shfl_xor(vx,2); vy+=__shfl_xor(vy,2);
      vx+=__shfl_xor(vx,4); vy+=__shfl_xor(vy,4);
      vx+=__shfl_xor(vx,8); vy+=__shfl_xor(vy,8);
      vx+=__shfl_xor(vx,16); vy+=__shfl_xor(vy,16);
      vx+=__shfl_xor(vx,32); vy+=__shfl_xor(vy,32);
      if (tid<2){ red[tid*2]=1.f/vx; red[tid*2+1]=1.f/vy; }   // 1/Se[0..3]
    }
    __syncthreads();                                   // sync 1

    // ---- B: rwl build (+psi in regs), Sw partials ----
    float psi=1.f;
    if (t>0){
      float rwv[4];
      #pragma unroll
      for (int i=0;i<4;i++){
        rwv[i] = en[i].y + mprev[i*3+1]*en[i].x*red[i];
        rwl[i*NSLOT+tid] = rwv[i];
      }
      psi=(1.f-prs[P_FG+0]*rwv[0])*(1.f-prs[P_FG+1]*rwv[1])
         *(1.f-prs[P_FG+2]*rwv[2])*(1.f-prs[P_FG+3]*rwv[3]);
    }
    if (t<NTT){ float v=red64s(ewv); if ((tid&63)==0) red[4+(tid>>6)]=v; }
    __syncthreads();                                   // sync 2

    // ---- C: RWP (t-1), out drain (t-2), ww final + usage + Sww partials ----
    if (t>0 && tid<256){
      int r=tid>>6, k=tid&63;
      float a=0.f;
      #pragma unroll
      for (int rr=0;rr<4;rr++){
        float4 rv=*(const float4*)&rwl[r*NSLOT+n0+rr*4];
        a += rv.x*Mem[(rr*4+0)*MSTR+k] + rv.y*Mem[(rr*4+1)*MSTR+k]
           + rv.z*Mem[(rr*4+2)*MSTR+k] + rv.w*Mem[(rr*4+3)*MSTR+k];
      }
      stg(qb+B_RWP+g*256+tid, a);
    }
    if (t>=2 && tid<256){
      float s=red32s(rwpv);
      if ((tid&31)==0) out[(size_t)(b*NTT+(t-2))*256 + g*8 + (tid>>5)] = s;
    }
    if (t==NTT) break;
    float wwv;
    {
      const float Sw=red[4]+red[5]+red[6]+red[7]+red[8]+red[9]+red[10]+red[11];
      const float isw=1.f/Sw;
      wwv=prs[P_WG]*(prs[P_AG]*al+(1.f-prs[P_AG])*ewv*isw);
      wwl[tid]=wwv;
      usagel[tid]=(usagel[tid]+wwv-usagel[tid]*wwv)*psi;
      float v=red64s(wwv);
      if ((tid&63)==0) red[12+(tid>>6)]=v;
    }
    __syncthreads();                                   // sync 3

    // ---- D: fused L/LT update + fwd/bwd; Mem update + rc + WM publish; alloc scan ----
    {
      float wn =wwl[n0+row];
      float pmn=precl[n0+row];
      float* Lr = &L[row*LSTR];
      float* Tr = &LT[row*LSTR];
      float fa0=0.f,fa1=0.f,fa2=0.f,fa3=0.f, ba0=0.f,ba1=0.f,ba2=0.f,ba3=0.f;
      #pragma unroll 2
      for (int jj=0;jj<4;jj++){
        int mb=(sub+32*jj)*4;
        float4 wm4=*(float4*)&wwl[mb];
        float4 pm4=*(float4*)&precl[mb];
        float c0=1.f-wn-wm4.x, c1=1.f-wn-wm4.y, c2=1.f-wn-wm4.z, c3=1.f-wn-wm4.w;
        int d=(n0+row)-mb;
        float4 l4=*(float4*)&Lr[mb];
        l4.x=c0*l4.x+wn*pm4.x; l4.y=c1*l4.y+wn*pm4.y;
        l4.z=c2*l4.z+wn*pm4.z; l4.w=c3*l4.w+wn*pm4.w;
        if (d>=0 && d<4) ((float*)&l4)[d]=0.f;
        *(float4*)&Lr[mb]=l4;
        float4 r0=*(const float4*)&rwl[0*NSLOT+mb];
        float4 r1=*(const float4*)&rwl[1*NSLOT+mb];
        float4 r2=*(const float4*)&rwl[2*NSLOT+mb];
        float4 r3=*(const float4*)&rwl[3*NSLOT+mb];
        fa0+=l4.x*r0.x+l4.y*r0.y+l4.z*r0.z+l4.w*r0.w;
        fa1+=l4.x*r1.x+l4.y*r1.y+l4.z*r1.z+l4.w*r1.w;
        fa2+=l4.x*r2.x+l4.y*r2.y+l4.z*r2.z+l4.w*r2.w;
        fa3+=l4.x*r3.x+l4.y*r3.y+l4.z*r3.z+l4.w*r3.w;
        float4 t4=*(float4*)&Tr[mb];
        t4.x=c0*t4.x+wm4.x*pmn; t4.y=c1*t4.y+wm4.y*pmn;
        t4.z=c2*t4.z+wm4.z*pmn; t4.w=c3*t4.w+wm4.w*pmn;
        if (d>=0 && d<4) ((float*)&t4)[d]=0.f;
        *(float4*)&Tr[mb]=t4;
        ba0+=t4.x*r0.x+t4.y*r0.y+t4.z*r0.z+t4.w*r0.w;
        ba1+=t4.x*r1.x+t4.y*r1.y+t4.z*r1.z+t4.w*r1.w;
        ba2+=t4.x*r2.x+t4.y*r2.y+t4.z*r2.z+t4.w*r2.w;
        ba3+=t4.x*r3.x+t4.y*r3.y+t4.z*r3.z+t4.w*r3.w;
      }
      fa0=red32s(fa0); fa1=red32s(fa1); fa2=red32s(fa2); fa3=red32s(fa3);
      ba0=red32s(ba0); ba1=red32s(ba1); ba2=red32s(ba2); ba3=red32s(ba3);
      if (sub==0){
        fwdb[0*NROW+row]=fa0; fwdb[1*NROW+row]=fa1; fwdb[2*NROW+row]=fa2; fwdb[3*NROW+row]=fa3;
        bwdb[0*NROW+row]=ba0; bwdb[1*NROW+row]=ba1; bwdb[2*NROW+row]=ba2; bwdb[3*NROW+row]=ba3;
      }
    }
    { // Mem update + rc dots + wd_{t+1} (prefetched wk2) + mnorm; f2 prs reads
      float wn=wwl[n0+row];
      float2 er =*(float2*)&prs[P_ERA+sub*2];
      float2 wvv=*(float2*)&prs[P_WV +sub*2];
      float m0=Mem[row*MSTR+sub*2+0], m1=Mem[row*MSTR+sub*2+1];
      m0=m0*(1.f-wn*er.x)+wn*wvv.x; m1=m1*(1.f-wn*er.y)+wn*wvv.y;
      Mem[row*MSTR+sub*2+0]=m0; Mem[row*MSTR+sub*2+1]=m1;
      float2 k0=*(float2*)&prs[  0+sub*2];
      float2 k1=*(float2*)&prs[ 64+sub*2];
      float2 k2=*(float2*)&prs[128+sub*2];
      float2 k3=*(float2*)&prs[192+sub*2];
      float rd0=m0*k0.x+m1*k0.y;
      float rd1=m0*k1.x+m1*k1.y;
      float rd2=m0*k2.x+m1*k2.y;
      float rd3=m0*k3.x+m1*k3.y;
      float ms=m0*m0+m1*m1;
      float wd=m0*wk2.x+m1*wk2.y;
      rd0=red32s(rd0); rd1=red32s(rd1); rd2=red32s(rd2); rd3=red32s(rd3);
      ms=red32s(ms); wd=red32s(wd);
      if (sub==0){
        float mn=sqrtf(ms);
        ern[0*NROW+row]=expf(prs[256]*rd0/(prs[P_RKN+0]*mn+EPSV));
        ern[1*NROW+row]=expf(prs[257]*rd1/(prs[P_RKN+1]*mn+EPSV));
        ern[2*NROW+row]=expf(prs[258]*rd2/(prs[P_RKN+2]*mn+EPSV));
        ern[3*NROW+row]=expf(prs[259]*rd3/(prs[480]*mn+EPSV));
        stg2(qb+B_WM+2*(n0+row), wd, mn);
      }
    }
    { // alloc_{t+1} scan (usage_t written in C, synced s3), f4 loads
      int n=n0+row;
      float u_n=usagel[n], pr=1.f;
      #pragma unroll
      for (int mb=0; mb<4; mb++){
        int m0=(sub+32*mb)*4;
        float4 u4=*(const float4*)&usagel[m0];
        pr *= (u4.x<u_n || (u4.x==u_n && m0  <n)) ? u4.x : 1.f;
        pr *= (u4.y<u_n || (u4.y==u_n && m0+1<n)) ? u4.y : 1.f;
        pr *= (u4.z<u_n || (u4.z==u_n && m0+2<n)) ? u4.z : 1.f;
        pr *= (u4.w<u_n || (u4.w==u_n && m0+3<n)) ? u4.w : 1.f;
      }
      pr=red32m(pr);
      if (sub==0) stg(qb+B_ALO+n, (1.f-u_n)*pr);
    }
    __syncthreads();                                   // sync 4

    // ---- F: prec update, EN/SEP publishes ----
    {
      const float Sww=red[12]+red[13]+red[14]+red[15]+red[16]+red[17]+red[18]+red[19];
      precl[tid]=(1.f-Sww)*precl[tid]+wwl[tid];
    }
    if (tid<64){
      int r=tid>>4, rw_=tid&15;
      float e=ern[r*NROW+rw_];
      float nn=mcur[r*3+0]*bwdb[r*NROW+rw_] + mcur[r*3+2]*fwdb[r*NROW+rw_];
      stg2(qb+B_EN+2*(r*NSLOT+n0+rw_), e, nn);
      float v=e;
      v+=__shfl_xor(v,1,16); v+=__shfl_xor(v,2,16);
      v+=__shfl_xor(v,4,16); v+=__shfl_xor(v,8,16);
      if (rw_==0) stg(qb+B_SEP+g*4+r, v);
    }

    // ---- early arrive: drain publishes, raise flag ----
    asm volatile("s_waitcnt vmcnt(0)" ::: "memory");
    __syncthreads();
    if (tid==0) __hip_atomic_store(flg+b*512+g*16, 3u+(unsigned)t, __ATOMIC_RELAXED, __HIP_MEMORY_SCOPE_AGENT);

    // ---- parse iface_{t+1} (hidden behind peers' arrival) ----
    if (t<NTT-1){
      const float* ifc = ws + (size_t)(b*NTT+(t+1))*NIF;
      float* mnx = modesA + 12*((t+1)&1);
      if (tid<324) prs[tid]=ifc[tid];
      __syncthreads();
      if (tid<4) prs[256+tid]=softpl(prs[256+tid]);
      else if (tid==4) prs[P_WS]=softpl(ifc[324]);
      else if (tid>=8 && tid<12) prs[P_FG+(tid-8)]=sigm(ifc[453+(tid-8)]);
      else if (tid==12) prs[P_AG]=sigm(ifc[457]);
      else if (tid==13) prs[P_WG]=sigm(ifc[458]);
      else if (tid>=16 && tid<20){
        int r=tid-16;
        float x0=ifc[459+r*3],x1=ifc[460+r*3],x2=ifc[461+r*3];
        float mx=fmaxf(x0,fmaxf(x1,x2));
        float e0=expf(x0-mx),e1=expf(x1-mx),e2=expf(x2-mx),s=e0+e1+e2;
        prs[P_MOD+r*3+0]=e0/s; prs[P_MOD+r*3+1]=e1/s; prs[P_MOD+r*3+2]=e2/s;
        mnx[r*3+0]=e0/s; mnx[r*3+1]=e1/s; mnx[r*3+2]=e2/s;
      }
      else if (tid>=64 && tid<128) prs[P_ERA+(tid-64)]=sigm(ifc[325+(tid-64)]);
      else if (tid>=192 && tid<256) prs[P_WV+(tid-192)]=ifc[389+(tid-192)];
      {
        int wv=tid>>6, lane=tid&63;
        if (wv<4){
          float v = (wv==0)? prs[260+lane] : prs[(wv-1)*64+lane];
          v = red64s(v*v);
          if (lane==0) prs[P_WKN+wv]=sqrtf(v);
          if (wv==0){
            float u=prs[192+lane];
            u=red64s(u*u);
            if (lane==0) prs[480]=sqrtf(u);
          }
        }
      }
    }

    // ---- late poll ----
    if (tid<GPB){
      while (__hip_atomic_load(flg+b*512+tid*16, __ATOMIC_RELAXED, __HIP_MEMORY_SCOPE_AGENT) < 3u+(unsigned)t)
        __builtin_amdgcn_s_sleep(1);
    }
    __syncthreads();
    asm volatile("" ::: "memory");
  }

  // final barrier: partials_15 published during drain phase
  lbar(flg, b, g, 3u+NTT, tid);
  if (tid<256){
    const float* fb = ws + IFCF + ((NTT+1)&1)*PARF + b*BATF;
    float v=ldc(fb+B_RWP+(tid&31)*256+g*8+(tid>>5));
    v=red32s(v);
    if ((tid&31)==0) out[(size_t)(b*NTT+(NTT-1))*256 + g*8 + (tid>>5)] = v;
  }
}

extern "C" void kernel_launch(void* const* d_in, const int* in_sizes, int n_in,
                              void* d_out, int out_size, void* d_ws, size_t ws_size,
                              hipStream_t stream)
{
  const float* ctrl=(const float*)d_in[0];
  const float* wif =(const float*)d_in[1];
  const float* bif =(const float*)d_in[2];
  const float* mem0=(const float*)d_in[3];
  float* outp=(float*)d_out;
  unsigned* flg=(unsigned*)d_ws;
  float* wsf=(float*)((char*)d_ws+32768);

  hipMemsetAsync(d_ws, 0, 32768, stream);   // zero generation flags each launch

  void* args[]={(void*)&ctrl,(void*)&wif,(void*)&bif,(void*)&mem0,(void*)&outp,(void*)&wsf,(void*)&flg};
  hipError_t err = hipLaunchCooperativeKernel((void*)dnc_kernel, dim3(NBLK), dim3(BS), args, 0, stream);
  if (err != hipSuccess){
    // fallback: plain launch (256 blocks @ 1 block/CU on 256 CUs — co-residency holds)
    hipLaunchKernelGGL(dnc_kernel, dim3(NBLK), dim3(BS), 0, stream,
                       ctrl, wif, bif, mem0, outp, wsf, flg);
  }
}